// Round 15
// baseline (89.132 us; speedup 1.0000x reference)
//
#include <hip/hip_runtime.h>
#include <hip/hip_bf16.h>

// InfoNCE loss, N=8192 D=512 C=128.
// Fixed-shift softmax (M=10): t_ij = s_ij/tau - 10 in [-20, 0].
//   Z_i  = sum_{class!=} e^{t_ij}
//   term = -t_p + log(Z + e^{t_p}) ~= -t_p + logZ + e^{t_p}/Z
// r14 -> r15: the K-loop is sync-window-bound (~2400cy fixed stall per
// barrier window regardless of MFMA content; r10/r12/r14 cross-evidence).
// Halve the windows: BK=128 bytes (NSTEP=4), ring-2 double buffer (64KB),
// one barrier per window, 32 i8-MFMA per wave per window. vmcnt(0) before
// each barrier waits on loads issued ~800cy earlier (L2-resident) -> ~free.
// Epilogue uses exp2f with log2e folded into the scale (ns accumulated in
// log2 units, converted by ln2 in k_rowterms). Everything else = r14.

constexpr int   D      = 512;
constexpr int   BT     = 128;
constexpr int   BK     = 128;        // bytes (i8 elems) per window
constexpr int   NSTEP  = D / BK;     // 4
constexpr float SHIFTL = 14.4269504088896340f;        // 10 * log2(e)
constexpr float QS2L   = 10.0f * 1.4426950408889634f / 16129.0f; // /tau/127^2*log2e
constexpr float LN2    = 0.6931471805599453f;

typedef __attribute__((ext_vector_type(4))) int i32x4;
typedef unsigned char uchar;
typedef unsigned long ulong_t;

__device__ inline void gload_lds16(const uchar* g, void* l) {
    __builtin_amdgcn_global_load_lds(
        (const __attribute__((address_space(1))) void*)g,
        (__attribute__((address_space(3))) void*)l, 16, 0, 0);
}

// ---------------- K1: L2-normalize rows, f32 -> i8 (+hist in block 0) ----
__global__ void k_normalize(const float* __restrict__ emb,
                            const int* __restrict__ classes,
                            uchar* __restrict__ normed,
                            int* __restrict__ hist, int n) {
    if (blockIdx.x == 0) {
        __shared__ int h[128];
        if (threadIdx.x < 128) h[threadIdx.x] = 0;
        __syncthreads();
        for (int i = threadIdx.x; i < n; i += 256)
            atomicAdd(&h[classes[i] & 127], 1);
        __syncthreads();
        if (threadIdx.x < 128) hist[threadIdx.x] = h[threadIdx.x];
    }
    int row  = blockIdx.x * 4 + (threadIdx.x >> 6);
    int lane = threadIdx.x & 63;
    if (row >= n) return;
    const float4* src = (const float4*)(emb + (size_t)row * D);
    float4 a = src[lane * 2];
    float4 b = src[lane * 2 + 1];
    float ss = a.x*a.x + a.y*a.y + a.z*a.z + a.w*a.w
             + b.x*b.x + b.y*b.y + b.z*b.z + b.w*b.w;
#pragma unroll
    for (int m = 1; m < 64; m <<= 1) ss += __shfl_xor(ss, m, 64);
    float sc = 127.0f / fmaxf(sqrtf(ss), 1e-12f);
    union { signed char c[8]; ulong_t u; } o;
    float v[8] = {a.x, a.y, a.z, a.w, b.x, b.y, b.z, b.w};
#pragma unroll
    for (int k = 0; k < 8; ++k) {
        int q = (int)rintf(v[k] * sc);
        q = q > 127 ? 127 : (q < -127 ? -127 : q);
        o.c[k] = (signed char)q;
    }
    *(ulong_t*)&normed[(size_t)row * D + lane * 8] = o.u;
}

// ---------------- K2: symmetric masked-exp i8 GEMM, BK=128, ring-2 --------
// Zpart: plane q in 0..2 (Z,NS2,P1), each [64 slots][n rows].
__global__ __launch_bounds__(256, 2) void k_zgemm(
    const uchar* __restrict__ normed, const int* __restrict__ classes,
    float* __restrict__ Zpart, int n, int nb, int npairs) {
    __shared__ char ring[2][32768];           // 64 KB: [buf][A0|B0|A1|B1 x 8KB]
    __shared__ int clsrow[BT], clscol[BT];

    const int tid  = threadIdx.x;
    const int lane = tid & 63;
    const int w    = tid >> 6;
    const int wm   = w >> 1, wn = w & 1;
    const int l15  = lane & 15, l4 = lane >> 4;
    const size_t QS = (size_t)64 * n;

    // XCD-chunked bijective swizzle
    int q8 = npairs >> 3, r8 = npairs & 7;
    int xcd = blockIdx.x & 7, off = blockIdx.x >> 3;
    int orig = (xcd < r8 ? xcd * (q8 + 1) : r8 * (q8 + 1) + (xcd - r8) * q8) + off;

    // orig -> (bi,bj) via 8x8 supertile walk (2D locality within an XCD)
    const int sgrid = nb >> 3;               // 8
    int idx = orig, si = 0;
    for (;;) { int rc = 36 + (sgrid - 1 - si) * 64; if (idx < rc) break; idx -= rc; ++si; }
    int bi, bj;
    if (idx < 36) { int u = 0, rem = 8; while (idx >= rem) { idx -= rem; ++u; --rem; }
                    bi = si * 8 + u; bj = si * 8 + u + idx; }
    else { idx -= 36; int sj = si + 1 + (idx >> 6); int v = idx & 63;
           bi = si * 8 + (v >> 3); bj = sj * 8 + (v & 7); }
    const int row0 = bi * BT, c0 = bj * BT;
    const bool diagblk = (bi == bj);

    if (tid < BT) clsrow[tid] = classes[row0 + tid];
    else          clscol[tid - BT] = classes[c0 + tid - BT];
    int crow[16];
#pragma unroll
    for (int t = 0; t < 16; ++t)
        crow[t] = classes[row0 + wm * 64 + (t >> 2) * 16 + l4 * 4 + (t & 3)];

    // staging: chunk = 16 rows x 64B (1KB). wave w owns chunks {2w,2w+1}
    // per matrix per k-half. source 16B slot pre-swizzled:
    // src16 = (l&3) ^ ((l>>3)&3) (involution), same as r14.
    const int src16 = (lane & 3) ^ ((lane >> 3) & 3);
    size_t gA[2], gB[2]; int lo[2];
#pragma unroll
    for (int it = 0; it < 2; ++it) {
        int chunk = w * 2 + it;
        int row   = chunk * 16 + (lane >> 2);
        gA[it] = (size_t)(row0 + row) * D + src16 * 16;
        gB[it] = (size_t)(c0   + row) * D + src16 * 16;
        lo[it] = chunk * 1024;
    }
    char* ringb = &ring[0][0];

    // stage one full 32KB window buffer (both 64B k-halves of A and B)
    auto STAGE = [&](int sbo, int kk) {       // kk = window * 128 (bytes)
#pragma unroll
        for (int h = 0; h < 2; ++h) {
            int kh = kk + h * 64;
            int so = sbo + h * 16384;
#pragma unroll
            for (int it = 0; it < 2; ++it) {
                gload_lds16(normed + gA[it] + kh, ringb + so + lo[it]);
                gload_lds16(normed + gB[it] + kh, ringb + so + 8192 + lo[it]);
            }
        }
    };

    i32x4 acc[4][4];
#pragma unroll
    for (int a = 0; a < 4; ++a)
#pragma unroll
        for (int b = 0; b < 4; ++b) acc[a][b] = (i32x4){0, 0, 0, 0};

    STAGE(0, 0);
    __builtin_amdgcn_sched_barrier(0);
    asm volatile("s_waitcnt vmcnt(0) lgkmcnt(0)" ::: "memory");
    __builtin_amdgcn_s_barrier();
    __builtin_amdgcn_sched_barrier(0);

    // b128 read: 16B slot = l4 ^ ((l15>>1)&3)  (conflict-free, r10-measured)
    const int rsw = (l15 >> 1) & 3;

#pragma unroll
    for (int kt = 0; kt < NSTEP; ++kt) {
        const int cur = kt & 1;
        // issue next window's stage first (max lead; target buffer's readers
        // finished before the barrier we just passed)
        if (kt + 1 < NSTEP) STAGE((cur ^ 1) * 32768, (kt + 1) * BK);
        const char* base = ringb + cur * 32768;
        i32x4 af[2][4], bfr[2][4];
#pragma unroll
        for (int h = 0; h < 2; ++h) {
            const char* la = base + h * 16384;
            const char* lb = la + 8192;
#pragma unroll
            for (int mf = 0; mf < 4; ++mf) {
                int ra = wm * 64 + mf * 16 + l15;
                af[h][mf] = *(const i32x4*)(la + ra * 64 + ((l4 ^ rsw) << 4));
            }
#pragma unroll
            for (int nf = 0; nf < 4; ++nf) {
                int rb = wn * 64 + nf * 16 + l15;
                bfr[h][nf] = *(const i32x4*)(lb + rb * 64 + ((l4 ^ rsw) << 4));
            }
        }
        __builtin_amdgcn_s_setprio(1);
#pragma unroll
        for (int h = 0; h < 2; ++h)
#pragma unroll
            for (int mf = 0; mf < 4; ++mf)
#pragma unroll
                for (int nf = 0; nf < 4; ++nf)
                    acc[mf][nf] = __builtin_amdgcn_mfma_i32_16x16x64_i8(
                        af[h][mf], bfr[h][nf], acc[mf][nf], 0, 0, 0);
        __builtin_amdgcn_s_setprio(0);
        __builtin_amdgcn_sched_barrier(0);
        if (kt + 1 < NSTEP) {
            asm volatile("s_waitcnt vmcnt(0)" ::: "memory");  // own stage landed
            __builtin_amdgcn_s_barrier();
            __builtin_amdgcn_sched_barrier(0);
        }
    }
    __syncthreads();   // full drain before LDS overlay

    // ---- epilogue: masked accumulation of (Z, NS2, P1), exp2 domain ----
    float cqz[4] = {0,0,0,0}, cqn[4] = {0,0,0,0}, cqp[4] = {0,0,0,0};
    float* redr = (float*)ringb;              // [2(wn)][128][3]
    float* redc = (float*)(ringb + 16384);    // [2(wm)][128][3]

#pragma unroll
    for (int mf = 0; mf < 4; ++mf) {
#pragma unroll
        for (int r = 0; r < 4; ++r) {
            int rr = wm * 64 + mf * 16 + l4 * 4 + r;
            int rg = row0 + rr;
            int cr = crow[mf * 4 + r];
            float z = 0.f, ns = 0.f, p1 = 0.f;
#pragma unroll
            for (int nf = 0; nf < 4; ++nf) {
                int cc = wn * 64 + nf * 16 + l15;
                float t = fmaf((float)acc[mf][nf][r], QS2L, -SHIFTL);
                float e = exp2f(t);
                bool same = (cr == clscol[cc]);
                bool dg   = (rg == c0 + cc);
                if (!same) { z += e; cqz[nf] += e; }
                else if (!dg) { ns += t; p1 += e; cqn[nf] += t; cqp[nf] += e; }
            }
#pragma unroll
            for (int m = 1; m < 16; m <<= 1) {
                z  += __shfl_xor(z,  m, 16);
                ns += __shfl_xor(ns, m, 16);
                p1 += __shfl_xor(p1, m, 16);
            }
            if (l15 == 0) {
                float* p = &redr[(wn * 128 + rr) * 3];
                p[0] = z; p[1] = ns; p[2] = p1;
            }
        }
    }
    if (!diagblk) {
#pragma unroll
        for (int nf = 0; nf < 4; ++nf) {
            float z = cqz[nf], nsv = cqn[nf], p = cqp[nf];
            z += __shfl_xor(z, 16, 64);  z += __shfl_xor(z, 32, 64);
            nsv += __shfl_xor(nsv, 16, 64); nsv += __shfl_xor(nsv, 32, 64);
            p += __shfl_xor(p, 16, 64);  p += __shfl_xor(p, 32, 64);
            if (l4 == 0) {
                float* pp = &redc[(wm * 128 + wn * 64 + nf * 16 + l15) * 3];
                pp[0] = z; pp[1] = nsv; pp[2] = p;
            }
        }
    }
    __syncthreads();

    if (tid < BT) {                           // row-side partials, slot = bj
#pragma unroll
        for (int q = 0; q < 3; ++q)
            Zpart[q * QS + (size_t)bj * n + row0 + tid] =
                redr[(0 * 128 + tid) * 3 + q] + redr[(1 * 128 + tid) * 3 + q];
    } else if (!diagblk) {                    // col-side partials, slot = bi
        int cc = tid - BT;
#pragma unroll
        for (int q = 0; q < 3; ++q)
            Zpart[q * QS + (size_t)bi * n + c0 + cc] =
                redc[(0 * 128 + cc) * 3 + q] + redc[(1 * 128 + cc) * 3 + q];
    }
}

// ---------------- K3: per-row closed-form terms ----------------
__global__ void k_rowterms(const float* __restrict__ Zpart,
                           const int* __restrict__ classes,
                           const int* __restrict__ hist,
                           float* __restrict__ rowloss,
                           float* __restrict__ rowcnt, int n) {
    int i = blockIdx.x * 256 + threadIdx.x;
    if (i >= n) return;
    const size_t QS = (size_t)64 * n;
    float z = 0.f, ns = 0.f, p1 = 0.f;
    for (int s = 0; s < 64; ++s) {
        size_t o = (size_t)s * n + i;
        z  += Zpart[o];
        ns += Zpart[QS + o];
        p1 += Zpart[2 * QS + o];
    }
    float c = (float)(hist[classes[i] & 127] - 1);
    rowloss[i] = -ns * LN2 + c * logf(z) + p1 / z;   // ns was in log2 units
    rowcnt[i]  = c;
}

// ---------------- K4: final deterministic reduction ----------------
__global__ void k_final(const float* __restrict__ rowloss,
                        const float* __restrict__ rowcnt,
                        float* __restrict__ out, int n) {
    __shared__ float sl[1024];
    __shared__ float sc[1024];
    float l = 0.f, c = 0.f;
    for (int i = threadIdx.x; i < n; i += 1024) {
        l += rowloss[i];
        c += rowcnt[i];
    }
    sl[threadIdx.x] = l;
    sc[threadIdx.x] = c;
    __syncthreads();
    for (int s = 512; s > 0; s >>= 1) {
        if (threadIdx.x < s) {
            sl[threadIdx.x] += sl[threadIdx.x + s];
            sc[threadIdx.x] += sc[threadIdx.x + s];
        }
        __syncthreads();
    }
    if (threadIdx.x == 0)
        out[0] = (sc[0] > 0.f) ? sl[0] / sc[0] : 0.f;
}

extern "C" void kernel_launch(void* const* d_in, const int* in_sizes, int n_in,
                              void* d_out, int out_size, void* d_ws, size_t ws_size,
                              hipStream_t stream) {
    const float* emb     = (const float*)d_in[0];
    const int*   classes = (const int*)d_in[1];
    float*       out     = (float*)d_out;
    const int n  = in_sizes[1];               // 8192
    const int nb = n / BT;                    // 64
    const int npairs = nb * (nb + 1) / 2;     // 2080

    uchar*  normed  = (uchar*)d_ws;                                    // 4 MB
    float*  Zpart   = (float*)((char*)d_ws + (size_t)n * D);           // 6 MB
    float*  rowloss = Zpart + (size_t)3 * 64 * n;
    float*  rowcnt  = rowloss + n;
    int*    hist    = (int*)(rowcnt + n);                              // 512 B

    k_normalize<<<n / 4, 256, 0, stream>>>(emb, classes, normed, hist, n);
    k_zgemm<<<npairs, 256, 0, stream>>>(normed, classes, Zpart, n, nb, npairs);
    k_rowterms<<<(n + 255) / 256, 256, 0, stream>>>(Zpart, classes, hist, rowloss, rowcnt, n);
    k_final<<<1, 1024, 0, stream>>>(rowloss, rowcnt, out, n);
}